// Round 6
// baseline (200.625 us; speedup 1.0000x reference)
//
#include <hip/hip_runtime.h>
#include <math.h>

#define SB 8
#define SS 2048
#define SH 768
#define ALPHA 0.5f

typedef __fp16 f16x8 __attribute__((ext_vector_type(8)));
typedef float f32x4 __attribute__((ext_vector_type(4)));

__device__ __forceinline__ float dot4(float4 a, float4 b) {
  return a.x*b.x + a.y*b.y + a.z*b.z + a.w*b.w;
}
__device__ __forceinline__ unsigned int pk2(float a, float b) {
  return __builtin_bit_cast(unsigned int, __builtin_amdgcn_cvt_pkrtz(a, b));
}

#define GLD(d, p, imm) \
  asm volatile("global_load_dwordx4 %0, %1, off offset:" #imm \
               : "=v"(d) : "v"(p) : "memory")
#define WAITV(n) asm volatile("s_waitcnt vmcnt(" #n ")" ::: "memory")
#define SB0() __builtin_amdgcn_sched_barrier(0)
// 6 B-slice loads: 32 halves (64 B) apart
#define ISSUE_B(B, P) do { \
  GLD(B[0],P,0);   GLD(B[1],P,64);  GLD(B[2],P,128); \
  GLD(B[3],P,192); GLD(B[4],P,256); GLD(B[5],P,320); } while (0)

// ws layout: Khs [SB*SS*SH] f16 (k_hat * km baked)  ~24 MB
//            | ksum [SB*SH] f32 | Nk[8] qsum[8] acc[8] cnt[8]

// K prep: 1024 blocks (XCD-swizzled like band), 16 K-rows/block, 4 rows/wave.
__global__ __launch_bounds__(256) void kprep_kernel(
    const float* __restrict__ K, const float* __restrict__ km,
    const float* __restrict__ qm,
    __fp16* __restrict__ Khs, float* __restrict__ ksum,
    float* __restrict__ Nk, float* __restrict__ qsum) {
  __shared__ float4 red[4][3][64];     // 12 KB
  int blk = blockIdx.x, t = threadIdx.x;
  int w = t >> 6, lane = t & 63;
  int work = (blk & 7) * 128 + (blk >> 3);   // batch -> XCD
  int b = work >> 7;
  int j0 = (work & 127) * 16;
  float4 acc0 = {0,0,0,0}, acc1 = {0,0,0,0}, acc2 = {0,0,0,0};
  for (int jj = 0; jj < 4; ++jj) {
    int j = j0 + 4 * w + jj;
    const float4* rp = (const float4*)(K + ((size_t)b * SS + j) * SH);
    float4 a = rp[lane], b4 = rp[lane + 64], c4 = rp[lane + 128];
    float ssv = dot4(a, a) + dot4(b4, b4) + dot4(c4, c4);
    #pragma unroll
    for (int m = 1; m < 64; m <<= 1) ssv += __shfl_xor(ssv, m, 64);
    float kwj = km[b * SS + j] / fmaxf(sqrtf(ssv), 1e-12f);
    uint2* kr = (uint2*)(Khs + ((size_t)b * SS + j) * SH);
    kr[lane]       = make_uint2(pk2(a.x*kwj,  a.y*kwj),  pk2(a.z*kwj,  a.w*kwj));
    kr[lane + 64]  = make_uint2(pk2(b4.x*kwj, b4.y*kwj), pk2(b4.z*kwj, b4.w*kwj));
    kr[lane + 128] = make_uint2(pk2(c4.x*kwj, c4.y*kwj), pk2(c4.z*kwj, c4.w*kwj));
    acc0.x += a.x*kwj;  acc0.y += a.y*kwj;  acc0.z += a.z*kwj;  acc0.w += a.w*kwj;
    acc1.x += b4.x*kwj; acc1.y += b4.y*kwj; acc1.z += b4.z*kwj; acc1.w += b4.w*kwj;
    acc2.x += c4.x*kwj; acc2.y += c4.y*kwj; acc2.z += c4.z*kwj; acc2.w += c4.w*kwj;
  }
  red[w][0][lane] = acc0; red[w][1][lane] = acc1; red[w][2][lane] = acc2;
  __syncthreads();
  if (t < 192) {
    int s = t >> 6, l = t & 63;
    float4 r0 = red[0][s][l], r1 = red[1][s][l], r2 = red[2][s][l], r3 = red[3][s][l];
    float* kp = ksum + b * SH + (s * 64 + l) * 4;
    atomicAdd(kp + 0, r0.x+r1.x+r2.x+r3.x);
    atomicAdd(kp + 1, r0.y+r1.y+r2.y+r3.y);
    atomicAdd(kp + 2, r0.z+r1.z+r2.z+r3.z);
    atomicAdd(kp + 3, r0.w+r1.w+r2.w+r3.w);
  }
  if (t < 16) {
    float pkm = km[b * SS + j0 + t];
    float pqm = qm[b * SS + j0 + t];
    #pragma unroll
    for (int m = 1; m < 16; m <<= 1) {
      pkm += __shfl_xor(pkm, m, 64);
      pqm += __shfl_xor(pqm, m, 64);
    }
    if (t == 0) { atomicAdd(&Nk[b], pkm); atomicAdd(&qsum[b], pqm); }
  }
}

// Band kernel: 1024 blocks, block = 16 q-rows, 4 waves K-split (192 each).
// Pinned-asm prologue + 2-deep counted-vmcnt B pipeline. Occupancy pinned to
// EXACTLY 4 waves/EU (VGPR budget 128) so the pinned double-buffer cannot be
// spilled to scratch -- r4/r5 showed the allocator targeting 8 waves/EU and
// spilling the pipeline (VGPR_Count 56), serializing every load.
__global__ __launch_bounds__(256)
__attribute__((amdgpu_waves_per_eu(4, 4)))
void band_kernel(
    const float* __restrict__ Q, const __fp16* __restrict__ Khs,
    const float* __restrict__ temp, const float* __restrict__ qm,
    const float* __restrict__ ksum, const float* __restrict__ Nkp,
    const float* __restrict__ qsum,
    float* __restrict__ acc, int* __restrict__ cnt, float* __restrict__ out) {
  __shared__ f32x4 sP[4][5][64];       // 20 KB: per-wave S-tile partials
  __shared__ float sSS[4][16], sDD[4][16];
  __shared__ float tab_s[64];
  int tid = threadIdx.x;
  int w = tid >> 6, lane = tid & 63;
  int l15 = lane & 15, quad = lane >> 4;
  int blk = blockIdx.x;
  int work = (blk & 7) * 128 + (blk >> 3);   // batch b -> XCD b
  int b = work >> 7;
  int i0 = (work & 127) * 16;

  if (tid < 64) {
    float invt = 1.0f / temp[0];
    tab_s[tid] = __expf(-ALPHA * fabsf((float)(tid - 31))) * invt;
  }
  float nk = Nkp[b];

  // ---- prologue: pinned Q loads (12) + ksum loads (12), all in flight
  const char* qpB = (const char*)(Q + ((size_t)b * SS + i0 + l15) * SH
                                  + w * 192 + quad * 8);
  const float* ksb = ksum + (size_t)b * SH + w * 192 + quad * 8;
  float4 xq[12];
  GLD(xq[0],qpB,0);    GLD(xq[1],qpB,16);   GLD(xq[2],qpB,128);
  GLD(xq[3],qpB,144);  GLD(xq[4],qpB,256);  GLD(xq[5],qpB,272);
  GLD(xq[6],qpB,384);  GLD(xq[7],qpB,400);  GLD(xq[8],qpB,512);
  GLD(xq[9],qpB,528);  GLD(xq[10],qpB,640); GLD(xq[11],qpB,656);
  float4 ks0[6], ks1[6];
  #pragma unroll
  for (int s = 0; s < 6; ++s) {
    ks0[s] = *(const float4*)(ksb + 32 * s);
    ks1[s] = *(const float4*)(ksb + 32 * s + 4);
  }
  WAITV(0); SB0();
  f16x8 afr[6];
  float ss = 0.f, dd = 0.f;
  #pragma unroll
  for (int s = 0; s < 6; ++s) {
    float4 x0 = xq[2*s], x1 = xq[2*s+1];
    ss += dot4(x0, x0) + dot4(x1, x1);
    dd += dot4(x0, ks0[s]) + dot4(x1, ks1[s]);
    uint4 u = make_uint4(pk2(x0.x, x0.y), pk2(x0.z, x0.w),
                         pk2(x1.x, x1.y), pk2(x1.z, x1.w));
    afr[s] = __builtin_bit_cast(f16x8, u);
  }
  // fold this wave's K-slice over quads; publish per-row partials
  ss += __shfl_xor(ss, 16, 64); ss += __shfl_xor(ss, 32, 64);
  dd += __shfl_xor(dd, 16, 64); dd += __shfl_xor(dd, 32, 64);
  if (quad == 0) { sSS[w][l15] = ss; sDD[w][l15] = dd; }

  // ---- 5 B-tiles, pinned 2-deep counted pipeline (12 outstanding max)
  const __fp16* KbH = Khs + (size_t)b * SS * SH;
  const char* pt[5];
  #pragma unroll
  for (int t = 0; t < 5; ++t) {
    int jc = min(max(i0 - 32 + 16 * t + l15, 0), SS - 1);
    pt[t] = (const char*)(KbH + (size_t)jc * SH + w * 192 + quad * 8);
  }
  f16x8 bqA[6], bqB[6];
  auto dotile = [&](f16x8* bq, int t) {
    f32x4 da = {0,0,0,0}, db = {0,0,0,0};
    da = __builtin_amdgcn_mfma_f32_16x16x32_f16(afr[0], bq[0], da, 0, 0, 0);
    db = __builtin_amdgcn_mfma_f32_16x16x32_f16(afr[1], bq[1], db, 0, 0, 0);
    da = __builtin_amdgcn_mfma_f32_16x16x32_f16(afr[2], bq[2], da, 0, 0, 0);
    db = __builtin_amdgcn_mfma_f32_16x16x32_f16(afr[3], bq[3], db, 0, 0, 0);
    da = __builtin_amdgcn_mfma_f32_16x16x32_f16(afr[4], bq[4], da, 0, 0, 0);
    db = __builtin_amdgcn_mfma_f32_16x16x32_f16(afr[5], bq[5], db, 0, 0, 0);
    sP[w][t][lane] = da + db;
  };
  ISSUE_B(bqA, pt[0]); ISSUE_B(bqB, pt[1]);
  WAITV(6); SB0(); dotile(bqA, 0); ISSUE_B(bqA, pt[2]);
  WAITV(6); SB0(); dotile(bqB, 1); ISSUE_B(bqB, pt[3]);
  WAITV(6); SB0(); dotile(bqA, 2); ISSUE_B(bqA, pt[4]);
  WAITV(6); SB0(); dotile(bqB, 3);
  WAITV(0); SB0(); dotile(bqA, 4);

  __syncthreads();                      // everything drained; one barrier total

  // ---- epilogue (all waves redundantly; lane fold at the end)
  float qws[4], d0s[4];
  #pragma unroll
  for (int reg = 0; reg < 4; ++reg) {
    int r = quad * 4 + reg;
    float ssr = sSS[0][r] + sSS[1][r] + sSS[2][r] + sSS[3][r];
    float ddr = sDD[0][r] + sDD[1][r] + sDD[2][r] + sDD[3][r];
    qws[reg] = qm[b * SS + i0 + r] / fmaxf(sqrtf(ssr), 1e-12f);
    d0s[reg] = ddr;
  }
  float an[4] = {0,0,0,0}, ad[4] = {0,0,0,0};
  #pragma unroll
  for (int t = 0; t < 5; ++t) {
    f32x4 v = sP[0][t][lane] + sP[1][t][lane] + sP[2][t][lane] + sP[3][t][lane];
    int j = i0 - 32 + 16 * t + l15;
    float vmask = ((unsigned)j < SS) ? 1.0f : 0.0f;
    int idxb = 16 * t + l15 - 1;        // = (j - i0) + 31
    #pragma unroll
    for (int reg = 0; reg < 4; ++reg) {
      float sv = v[reg] * qws[reg];     // kw baked into Khs
      int idx = min(max(idxb - quad * 4 - reg, 0), 63);
      float ev = (__expf(sv * tab_s[idx]) - 1.0f) * vmask;
      an[reg] += ev * sv;
      ad[reg] += ev;
    }
  }
  float tot = 0.f;
  #pragma unroll
  for (int reg = 0; reg < 4; ++reg) {
    float a = an[reg], e = ad[reg];
    a += __shfl_xor(a, 1, 64); a += __shfl_xor(a, 2, 64);
    a += __shfl_xor(a, 4, 64); a += __shfl_xor(a, 8, 64);
    e += __shfl_xor(e, 1, 64); e += __shfl_xor(e, 2, 64);
    e += __shfl_xor(e, 4, 64); e += __shfl_xor(e, 8, 64);
    tot += (qws[reg] * d0s[reg] + a) / (nk + e);
  }
  tot += __shfl_xor(tot, 16, 64);       // sum the 4 quads' row-groups
  tot += __shfl_xor(tot, 32, 64);
  if (tid == 0) {
    atomicAdd(&acc[b], tot);
    __threadfence();
    if (atomicAdd(&cnt[b], 1) == 127) { // last of 128 blocks for batch b
      float a2 = atomicAdd(&acc[b], 0.0f);
      out[b] = a2 / fmaxf(qsum[b], 1.0f);
    }
  }
}

extern "C" void kernel_launch(void* const* d_in, const int* in_sizes, int n_in,
                              void* d_out, int out_size, void* d_ws, size_t ws_size,
                              hipStream_t stream) {
  const float* Q    = (const float*)d_in[0];
  const float* K    = (const float*)d_in[1];
  const float* qm   = (const float*)d_in[2];
  const float* km   = (const float*)d_in[3];
  const float* temp = (const float*)d_in[4];
  float* outp = (float*)d_out;

  const size_t KHS_BYTES = (size_t)SB * SS * SH * 2;  // ~24 MB (fits ws, proven)
  __fp16* Khs = (__fp16*)d_ws;
  float* ksum = (float*)((char*)d_ws + KHS_BYTES);
  float* Nk   = ksum + SB * SH;
  float* qsum = Nk + 8;
  float* accb = qsum + 8;
  int*   cnt  = (int*)(accb + 8);

  (void)hipMemsetAsync(ksum, 0, (SB * SH + 32) * sizeof(float), stream);

  kprep_kernel<<<1024, 256, 0, stream>>>(K, km, qm, Khs, ksum, Nk, qsum);
  band_kernel<<<1024, 256, 0, stream>>>(Q, Khs, temp, qm, ksum, Nk,
                                        qsum, accb, cnt, outp);
}

// Round 7
// 185.139 us; speedup vs baseline: 1.0836x; 1.0836x over previous
//
#include <hip/hip_runtime.h>
#include <math.h>

#define SB 8
#define SS 2048
#define SH 768
#define ALPHA 0.5f

typedef __fp16 f16x8 __attribute__((ext_vector_type(8)));
typedef float f32x4 __attribute__((ext_vector_type(4)));

__device__ __forceinline__ float dot4(float4 a, float4 b) {
  return a.x*b.x + a.y*b.y + a.z*b.z + a.w*b.w;
}
__device__ __forceinline__ unsigned int pk2(float a, float b) {
  return __builtin_bit_cast(unsigned int, __builtin_amdgcn_cvt_pkrtz(a, b));
}

#define GLD(d, p, imm) \
  asm volatile("global_load_dwordx4 %0, %1, off offset:" #imm \
               : "=v"(d) : "v"(p) : "memory")
#define WAITV(n) asm volatile("s_waitcnt vmcnt(" #n ")" ::: "memory")
#define SB0() __builtin_amdgcn_sched_barrier(0)

// 6 B-slice loads into NAMED regs (no arrays -> no scratch; rule #20)
#define ISSUE6(P, R0, R1, R2, R3, R4, R5) do { \
  GLD(R0, P, 0);   GLD(R1, P, 64);  GLD(R2, P, 128); \
  GLD(R3, P, 192); GLD(R4, P, 256); GLD(R5, P, 320); } while (0)

#define MFMA(a, b, c) __builtin_amdgcn_mfma_f32_16x16x32_f16(a, b, c, 0, 0, 0)

// one 16x16 S-tile from named B regs; literal tile index t
#define FTILE(t, R0, R1, R2, R3, R4, R5) do { \
  f32x4 da_ = {0,0,0,0}, db_ = {0,0,0,0}; \
  da_ = MFMA(a0, R0, da_); db_ = MFMA(a1, R1, db_); \
  da_ = MFMA(a2, R2, da_); db_ = MFMA(a3, R3, db_); \
  da_ = MFMA(a4, R4, da_); db_ = MFMA(a5, R5, db_); \
  sP[w][t][lane] = da_ + db_; } while (0)

// ws layout: Khs [SB*SS*SH] f16 (k_hat * km baked)  ~24 MB
//            | ksum [SB*SH] f32 | Nk[8] qsum[8] acc[8] cnt[8]

// K prep (r2-exact): grid (64, SB), block 256 = 4 waves x 8 rows.
__global__ __launch_bounds__(256) void kprep_kernel(
    const float* __restrict__ K, const float* __restrict__ km,
    const float* __restrict__ qm,
    __fp16* __restrict__ Khs, float* __restrict__ ksum,
    float* __restrict__ Nk, float* __restrict__ qsum) {
  __shared__ float4 red[4][3][64];     // 12 KB
  int b = blockIdx.y, jc = blockIdx.x, t = threadIdx.x;
  int w = t >> 6, lane = t & 63;
  int j0 = jc * 32;
  float4 acc0 = {0,0,0,0}, acc1 = {0,0,0,0}, acc2 = {0,0,0,0};
  for (int jj = 0; jj < 8; ++jj) {
    int j = j0 + 8 * w + jj;
    const float4* rp = (const float4*)(K + ((size_t)b * SS + j) * SH);
    float4 a = rp[lane], b4 = rp[lane + 64], c4 = rp[lane + 128];
    float ssv = dot4(a, a) + dot4(b4, b4) + dot4(c4, c4);
    #pragma unroll
    for (int m = 1; m < 64; m <<= 1) ssv += __shfl_xor(ssv, m, 64);
    float kwj = km[b * SS + j] / fmaxf(sqrtf(ssv), 1e-12f);
    uint2* kr = (uint2*)(Khs + ((size_t)b * SS + j) * SH);
    kr[lane]       = make_uint2(pk2(a.x*kwj,  a.y*kwj),  pk2(a.z*kwj,  a.w*kwj));
    kr[lane + 64]  = make_uint2(pk2(b4.x*kwj, b4.y*kwj), pk2(b4.z*kwj, b4.w*kwj));
    kr[lane + 128] = make_uint2(pk2(c4.x*kwj, c4.y*kwj), pk2(c4.z*kwj, c4.w*kwj));
    acc0.x += a.x*kwj;  acc0.y += a.y*kwj;  acc0.z += a.z*kwj;  acc0.w += a.w*kwj;
    acc1.x += b4.x*kwj; acc1.y += b4.y*kwj; acc1.z += b4.z*kwj; acc1.w += b4.w*kwj;
    acc2.x += c4.x*kwj; acc2.y += c4.y*kwj; acc2.z += c4.z*kwj; acc2.w += c4.w*kwj;
  }
  red[w][0][lane] = acc0; red[w][1][lane] = acc1; red[w][2][lane] = acc2;
  __syncthreads();
  if (t < 192) {
    int s = t >> 6, l = t & 63;
    float4 r0 = red[0][s][l], r1 = red[1][s][l], r2 = red[2][s][l], r3 = red[3][s][l];
    float* kp = ksum + b * SH + (s * 64 + l) * 4;
    atomicAdd(kp + 0, r0.x+r1.x+r2.x+r3.x);
    atomicAdd(kp + 1, r0.y+r1.y+r2.y+r3.y);
    atomicAdd(kp + 2, r0.z+r1.z+r2.z+r3.z);
    atomicAdd(kp + 3, r0.w+r1.w+r2.w+r3.w);
  }
  if (t < 32) {
    float pkm = km[b * SS + j0 + t];
    float pqm = qm[b * SS + j0 + t];
    #pragma unroll
    for (int m = 1; m < 32; m <<= 1) {
      pkm += __shfl_xor(pkm, m, 64);
      pqm += __shfl_xor(pqm, m, 64);
    }
    if (t == 0) { atomicAdd(&Nk[b], pkm); atomicAdd(&qsum[b], pqm); }
  }
}

// Band kernel: 1024 blocks, 16 q-rows/block, 4 waves K-split (192 each).
// FULLY FLATTENED: named registers only in the pinned-asm pipeline (r3-r6
// passed buffer arrays by pointer -> scratch allocation (VGPR_Count 56) ->
// every load serialized through scratch; rule #20).
__global__ __launch_bounds__(256)
__attribute__((amdgpu_waves_per_eu(4, 4)))
void band_kernel(
    const float* __restrict__ Q, const __fp16* __restrict__ Khs,
    const float* __restrict__ temp, const float* __restrict__ qm,
    const float* __restrict__ ksum, const float* __restrict__ Nkp,
    const float* __restrict__ qsum,
    float* __restrict__ acc, int* __restrict__ cnt, float* __restrict__ out) {
  __shared__ f32x4 sP[4][5][64];       // 20 KB: per-wave S-tile partials
  __shared__ float sSS[4][16], sDD[4][16];
  __shared__ float tab_s[64];
  int tid = threadIdx.x;
  int w = tid >> 6, lane = tid & 63;
  int l15 = lane & 15, quad = lane >> 4;
  int blk = blockIdx.x;
  int work = (blk & 7) * 128 + (blk >> 3);   // batch b -> XCD b
  int b = work >> 7;
  int i0 = (work & 127) * 16;

  if (tid < 64) {
    float invt = 1.0f / temp[0];
    tab_s[tid] = __expf(-ALPHA * fabsf((float)(tid - 31))) * invt;
  }
  float nk = Nkp[b];

  // ---- prologue: 12 pinned Q loads + 12 ksum loads, all in flight
  const char* qpB = (const char*)(Q + ((size_t)b * SS + i0 + l15) * SH
                                  + w * 192 + quad * 8);
  const float* ksb = ksum + (size_t)b * SH + w * 192 + quad * 8;
  float4 x0, x1, x2, x3, x4, x5, x6, x7, x8, x9, x10, x11;
  GLD(x0, qpB, 0);    GLD(x1, qpB, 16);   GLD(x2, qpB, 128);
  GLD(x3, qpB, 144);  GLD(x4, qpB, 256);  GLD(x5, qpB, 272);
  GLD(x6, qpB, 384);  GLD(x7, qpB, 400);  GLD(x8, qpB, 512);
  GLD(x9, qpB, 528);  GLD(x10, qpB, 640); GLD(x11, qpB, 656);
  float4 g0  = *(const float4*)(ksb + 0);
  float4 g1  = *(const float4*)(ksb + 4);
  float4 g2  = *(const float4*)(ksb + 32);
  float4 g3  = *(const float4*)(ksb + 36);
  float4 g4  = *(const float4*)(ksb + 64);
  float4 g5  = *(const float4*)(ksb + 68);
  float4 g6  = *(const float4*)(ksb + 96);
  float4 g7  = *(const float4*)(ksb + 100);
  float4 g8  = *(const float4*)(ksb + 128);
  float4 g9  = *(const float4*)(ksb + 132);
  float4 g10 = *(const float4*)(ksb + 160);
  float4 g11 = *(const float4*)(ksb + 164);
  WAITV(0); SB0();

  float ss = dot4(x0,x0) + dot4(x1,x1) + dot4(x2,x2) + dot4(x3,x3)
           + dot4(x4,x4) + dot4(x5,x5) + dot4(x6,x6) + dot4(x7,x7)
           + dot4(x8,x8) + dot4(x9,x9) + dot4(x10,x10) + dot4(x11,x11);
  float dd = dot4(x0,g0) + dot4(x1,g1) + dot4(x2,g2) + dot4(x3,g3)
           + dot4(x4,g4) + dot4(x5,g5) + dot4(x6,g6) + dot4(x7,g7)
           + dot4(x8,g8) + dot4(x9,g9) + dot4(x10,g10) + dot4(x11,g11);
  #define MKA(a, xA, xB) do { \
    uint4 u_ = make_uint4(pk2(xA.x, xA.y), pk2(xA.z, xA.w), \
                          pk2(xB.x, xB.y), pk2(xB.z, xB.w)); \
    a = __builtin_bit_cast(f16x8, u_); } while (0)
  f16x8 a0, a1, a2, a3, a4, a5;
  MKA(a0, x0, x1); MKA(a1, x2, x3); MKA(a2, x4, x5);
  MKA(a3, x6, x7); MKA(a4, x8, x9); MKA(a5, x10, x11);

  // fold this wave's K-slice over quads; publish per-row partials
  ss += __shfl_xor(ss, 16, 64); ss += __shfl_xor(ss, 32, 64);
  dd += __shfl_xor(dd, 16, 64); dd += __shfl_xor(dd, 32, 64);
  if (quad == 0) { sSS[w][l15] = ss; sDD[w][l15] = dd; }

  // ---- 5 B-tiles, named-reg 2-deep counted-vmcnt pipeline
  const __fp16* KbH = Khs + (size_t)b * SS * SH;
  int jc0 = min(max(i0 - 32 + l15, 0), SS - 1);
  int jc1 = min(max(i0 - 16 + l15, 0), SS - 1);
  int jc2 = i0 + l15;                        // always in range
  int jc3 = min(i0 + 16 + l15, SS - 1);
  int jc4 = min(i0 + 32 + l15, SS - 1);
  const char* pt0 = (const char*)(KbH + (size_t)jc0 * SH + w * 192 + quad * 8);
  const char* pt1 = (const char*)(KbH + (size_t)jc1 * SH + w * 192 + quad * 8);
  const char* pt2 = (const char*)(KbH + (size_t)jc2 * SH + w * 192 + quad * 8);
  const char* pt3 = (const char*)(KbH + (size_t)jc3 * SH + w * 192 + quad * 8);
  const char* pt4 = (const char*)(KbH + (size_t)jc4 * SH + w * 192 + quad * 8);

  f16x8 B0, B1, B2, B3, B4, B5, C0, C1, C2, C3, C4, C5;
  ISSUE6(pt0, B0, B1, B2, B3, B4, B5);
  ISSUE6(pt1, C0, C1, C2, C3, C4, C5);
  WAITV(6); SB0(); FTILE(0, B0, B1, B2, B3, B4, B5);
  ISSUE6(pt2, B0, B1, B2, B3, B4, B5);
  WAITV(6); SB0(); FTILE(1, C0, C1, C2, C3, C4, C5);
  ISSUE6(pt3, C0, C1, C2, C3, C4, C5);
  WAITV(6); SB0(); FTILE(2, B0, B1, B2, B3, B4, B5);
  ISSUE6(pt4, B0, B1, B2, B3, B4, B5);
  WAITV(6); SB0(); FTILE(3, C0, C1, C2, C3, C4, C5);
  WAITV(0); SB0(); FTILE(4, B0, B1, B2, B3, B4, B5);

  __syncthreads();                      // everything drained; one barrier total

  // ---- epilogue (all waves redundantly; lane fold at the end)
  float qws[4], d0s[4];
  #pragma unroll
  for (int reg = 0; reg < 4; ++reg) {
    int r = quad * 4 + reg;
    float ssr = sSS[0][r] + sSS[1][r] + sSS[2][r] + sSS[3][r];
    float ddr = sDD[0][r] + sDD[1][r] + sDD[2][r] + sDD[3][r];
    qws[reg] = qm[b * SS + i0 + r] / fmaxf(sqrtf(ssr), 1e-12f);
    d0s[reg] = ddr;
  }
  float an[4] = {0,0,0,0}, ad[4] = {0,0,0,0};
  #pragma unroll
  for (int t = 0; t < 5; ++t) {
    f32x4 v = sP[0][t][lane] + sP[1][t][lane] + sP[2][t][lane] + sP[3][t][lane];
    int j = i0 - 32 + 16 * t + l15;
    float vmask = ((unsigned)j < SS) ? 1.0f : 0.0f;
    int idxb = 16 * t + l15 - 1;        // = (j - i0) + 31
    #pragma unroll
    for (int reg = 0; reg < 4; ++reg) {
      float sv = v[reg] * qws[reg];     // kw baked into Khs
      int idx = min(max(idxb - quad * 4 - reg, 0), 63);
      float ev = (__expf(sv * tab_s[idx]) - 1.0f) * vmask;
      an[reg] += ev * sv;
      ad[reg] += ev;
    }
  }
  float tot = 0.f;
  #pragma unroll
  for (int reg = 0; reg < 4; ++reg) {
    float a = an[reg], e = ad[reg];
    a += __shfl_xor(a, 1, 64); a += __shfl_xor(a, 2, 64);
    a += __shfl_xor(a, 4, 64); a += __shfl_xor(a, 8, 64);
    e += __shfl_xor(e, 1, 64); e += __shfl_xor(e, 2, 64);
    e += __shfl_xor(e, 4, 64); e += __shfl_xor(e, 8, 64);
    tot += (qws[reg] * d0s[reg] + a) / (nk + e);
  }
  tot += __shfl_xor(tot, 16, 64);       // sum the 4 quads' row-groups
  tot += __shfl_xor(tot, 32, 64);
  if (tid == 0) {
    atomicAdd(&acc[b], tot);
    __threadfence();
    if (atomicAdd(&cnt[b], 1) == 127) { // last of 128 blocks for batch b
      float a2 = atomicAdd(&acc[b], 0.0f);
      out[b] = a2 / fmaxf(qsum[b], 1.0f);
    }
  }
}

extern "C" void kernel_launch(void* const* d_in, const int* in_sizes, int n_in,
                              void* d_out, int out_size, void* d_ws, size_t ws_size,
                              hipStream_t stream) {
  const float* Q    = (const float*)d_in[0];
  const float* K    = (const float*)d_in[1];
  const float* qm   = (const float*)d_in[2];
  const float* km   = (const float*)d_in[3];
  const float* temp = (const float*)d_in[4];
  float* outp = (float*)d_out;

  const size_t KHS_BYTES = (size_t)SB * SS * SH * 2;  // ~24 MB (fits ws, proven)
  __fp16* Khs = (__fp16*)d_ws;
  float* ksum = (float*)((char*)d_ws + KHS_BYTES);
  float* Nk   = ksum + SB * SH;
  float* qsum = Nk + 8;
  float* accb = qsum + 8;
  int*   cnt  = (int*)(accb + 8);

  (void)hipMemsetAsync(ksum, 0, (SB * SH + 32) * sizeof(float), stream);

  kprep_kernel<<<dim3(64, SB), 256, 0, stream>>>(K, km, qm, Khs, ksum, Nk, qsum);
  band_kernel<<<1024, 256, 0, stream>>>(Q, Khs, temp, qm, ksum, Nk,
                                        qsum, accb, cnt, outp);
}

// Round 8
// 181.870 us; speedup vs baseline: 1.1031x; 1.0180x over previous
//
#include <hip/hip_runtime.h>
#include <math.h>

#define SB 8
#define SS 2048
#define SH 768
#define ALPHA 0.5f

typedef __fp16 f16x8 __attribute__((ext_vector_type(8)));
typedef float f32x4 __attribute__((ext_vector_type(4)));

__device__ __forceinline__ float dot4(float4 a, float4 b) {
  return a.x*b.x + a.y*b.y + a.z*b.z + a.w*b.w;
}
__device__ __forceinline__ unsigned int pk2(float a, float b) {
  return __builtin_bit_cast(unsigned int, __builtin_amdgcn_cvt_pkrtz(a, b));
}
#define MFMA(a, b, c) __builtin_amdgcn_mfma_f32_16x16x32_f16(a, b, c, 0, 0, 0)

// ws layout: Khs [SB*SS*SH] f16 (k_hat * km baked)  ~24 MB
//            | ksum [SB*SH] f32 | Nk[8] qsum[8] acc[8] cnt[8]

// K prep (r2-exact, proven): grid (64, SB), block 256 = 4 waves x 8 rows.
__global__ __launch_bounds__(256) void kprep_kernel(
    const float* __restrict__ K, const float* __restrict__ km,
    const float* __restrict__ qm,
    __fp16* __restrict__ Khs, float* __restrict__ ksum,
    float* __restrict__ Nk, float* __restrict__ qsum) {
  __shared__ float4 red[4][3][64];     // 12 KB
  int b = blockIdx.y, jc = blockIdx.x, t = threadIdx.x;
  int w = t >> 6, lane = t & 63;
  int j0 = jc * 32;
  float4 acc0 = {0,0,0,0}, acc1 = {0,0,0,0}, acc2 = {0,0,0,0};
  for (int jj = 0; jj < 8; ++jj) {
    int j = j0 + 8 * w + jj;
    const float4* rp = (const float4*)(K + ((size_t)b * SS + j) * SH);
    float4 a = rp[lane], b4 = rp[lane + 64], c4 = rp[lane + 128];
    float ssv = dot4(a, a) + dot4(b4, b4) + dot4(c4, c4);
    #pragma unroll
    for (int m = 1; m < 64; m <<= 1) ssv += __shfl_xor(ssv, m, 64);
    float kwj = km[b * SS + j] / fmaxf(sqrtf(ssv), 1e-12f);
    uint2* kr = (uint2*)(Khs + ((size_t)b * SS + j) * SH);
    kr[lane]       = make_uint2(pk2(a.x*kwj,  a.y*kwj),  pk2(a.z*kwj,  a.w*kwj));
    kr[lane + 64]  = make_uint2(pk2(b4.x*kwj, b4.y*kwj), pk2(b4.z*kwj, b4.w*kwj));
    kr[lane + 128] = make_uint2(pk2(c4.x*kwj, c4.y*kwj), pk2(c4.z*kwj, c4.w*kwj));
    acc0.x += a.x*kwj;  acc0.y += a.y*kwj;  acc0.z += a.z*kwj;  acc0.w += a.w*kwj;
    acc1.x += b4.x*kwj; acc1.y += b4.y*kwj; acc1.z += b4.z*kwj; acc1.w += b4.w*kwj;
    acc2.x += c4.x*kwj; acc2.y += c4.y*kwj; acc2.z += c4.z*kwj; acc2.w += c4.w*kwj;
  }
  red[w][0][lane] = acc0; red[w][1][lane] = acc1; red[w][2][lane] = acc2;
  __syncthreads();
  if (t < 192) {
    int s = t >> 6, l = t & 63;
    float4 r0 = red[0][s][l], r1 = red[1][s][l], r2 = red[2][s][l], r3 = red[3][s][l];
    float* kp = ksum + b * SH + (s * 64 + l) * 4;
    atomicAdd(kp + 0, r0.x+r1.x+r2.x+r3.x);
    atomicAdd(kp + 1, r0.y+r1.y+r2.y+r3.y);
    atomicAdd(kp + 2, r0.z+r1.z+r2.z+r3.z);
    atomicAdd(kp + 3, r0.w+r1.w+r2.w+r3.w);
  }
  if (t < 32) {
    float pkm = km[b * SS + j0 + t];
    float pqm = qm[b * SS + j0 + t];
    #pragma unroll
    for (int m = 1; m < 32; m <<= 1) {
      pkm += __shfl_xor(pkm, m, 64);
      pqm += __shfl_xor(pqm, m, 64);
    }
    if (t == 0) { atomicAdd(&Nk[b], pkm); atomicAdd(&qsum[b], pqm); }
  }
}

// Band kernel v8: 1024 blocks x 512 threads (8 waves), 16 q-rows/block,
// K split 8 x 96 per wave. DELIBERATELY LOW register footprint (~60 live:
// A=3xf16x8, B transient, 5 f32x4 tile accs) -- every prior round spilled
// ~250 B/thread (WRITE_SIZE 16.5-64.5 MB = scratch) once live state neared
// ~100 VGPRs, and the spill round-trips were the 50-65us serial chain.
// No inline asm anywhere; plain loads, compiler-scheduled.
__global__ __launch_bounds__(512, 1) void band_kernel(
    const float* __restrict__ Q, const __fp16* __restrict__ Khs,
    const float* __restrict__ temp, const float* __restrict__ qm,
    const float* __restrict__ ksum, const float* __restrict__ Nkp,
    const float* __restrict__ qsum,
    float* __restrict__ acc, int* __restrict__ cnt, float* __restrict__ out) {
  __shared__ f32x4 sPc[4][5][64];      // 20 KB: pair-combined S partials
  __shared__ float sSS[8][16], sDD[8][16];   // 1 KB
  __shared__ float tab_s[64];
  int tid = threadIdx.x;
  int w = tid >> 6, lane = tid & 63;
  int l15 = lane & 15, quad = lane >> 4;
  int blk = blockIdx.x;
  int work = (blk & 7) * 128 + (blk >> 3);   // batch b -> XCD b
  int b = work >> 7;
  int i0 = (work & 127) * 16;

  if (tid < 64) {
    float invt = 1.0f / temp[0];
    tab_s[tid] = __expf(-ALPHA * fabsf((float)(tid - 31))) * invt;
  }
  float nk = Nkp[b];
  // per-row qm for this lane's epilogue rows (quad*4 + 0..3)
  float qm0 = qm[b * SS + i0 + quad * 4 + 0];
  float qm1 = qm[b * SS + i0 + quad * 4 + 1];
  float qm2 = qm[b * SS + i0 + quad * 4 + 2];
  float qm3 = qm[b * SS + i0 + quad * 4 + 3];

  // ---- prologue: this wave's 96-col K-slice of Q row l15
  const float* qp = Q + ((size_t)b * SS + i0 + l15) * SH + w * 96 + quad * 8;
  const float* kp = ksum + (size_t)b * SH + w * 96 + quad * 8;
  float4 x0 = *(const float4*)(qp + 0),  x1 = *(const float4*)(qp + 4);
  float4 x2 = *(const float4*)(qp + 32), x3 = *(const float4*)(qp + 36);
  float4 x4 = *(const float4*)(qp + 64), x5 = *(const float4*)(qp + 68);
  float4 g0 = *(const float4*)(kp + 0),  g1 = *(const float4*)(kp + 4);
  float4 g2 = *(const float4*)(kp + 32), g3 = *(const float4*)(kp + 36);
  float4 g4 = *(const float4*)(kp + 64), g5 = *(const float4*)(kp + 68);
  float ss = dot4(x0,x0) + dot4(x1,x1) + dot4(x2,x2)
           + dot4(x3,x3) + dot4(x4,x4) + dot4(x5,x5);
  float dd = dot4(x0,g0) + dot4(x1,g1) + dot4(x2,g2)
           + dot4(x3,g3) + dot4(x4,g4) + dot4(x5,g5);
  #define MKA(a, xA, xB) do { \
    uint4 u_ = make_uint4(pk2(xA.x, xA.y), pk2(xA.z, xA.w), \
                          pk2(xB.x, xB.y), pk2(xB.z, xB.w)); \
    a = __builtin_bit_cast(f16x8, u_); } while (0)
  f16x8 a0, a1, a2;
  MKA(a0, x0, x1); MKA(a1, x2, x3); MKA(a2, x4, x5);
  ss += __shfl_xor(ss, 16, 64); ss += __shfl_xor(ss, 32, 64);
  dd += __shfl_xor(dd, 16, 64); dd += __shfl_xor(dd, 32, 64);
  if (quad == 0) { sSS[w][l15] = ss; sDD[w][l15] = dd; }

  // ---- 5 S-tiles, B direct from Khs (this wave's 96-col slice)
  const __fp16* KbH = Khs + (size_t)b * SS * SH;
  f32x4 d0t, d1t, d2t, d3t, d4t;
  #define DOTILE(DT, T) do { \
    int jc_ = min(max(i0 - 32 + 16 * (T) + l15, 0), SS - 1); \
    const __fp16* bp_ = KbH + (size_t)jc_ * SH + w * 96 + quad * 8; \
    f16x8 b0_ = *(const f16x8*)(bp_); \
    f16x8 b1_ = *(const f16x8*)(bp_ + 32); \
    f16x8 b2_ = *(const f16x8*)(bp_ + 64); \
    f32x4 d_ = {0,0,0,0}; \
    d_ = MFMA(a0, b0_, d_); d_ = MFMA(a1, b1_, d_); d_ = MFMA(a2, b2_, d_); \
    DT = d_; } while (0)
  DOTILE(d0t, 0); DOTILE(d1t, 1); DOTILE(d2t, 2); DOTILE(d3t, 3); DOTILE(d4t, 4);

  // ---- pair-combine K partials: waves 0-3 write, waves 4-7 add
  if (w < 4) {
    sPc[w][0][lane] = d0t; sPc[w][1][lane] = d1t; sPc[w][2][lane] = d2t;
    sPc[w][3][lane] = d3t; sPc[w][4][lane] = d4t;
  }
  __syncthreads();
  if (w >= 4) {
    sPc[w-4][0][lane] += d0t; sPc[w-4][1][lane] += d1t;
    sPc[w-4][2][lane] += d2t; sPc[w-4][3][lane] += d3t;
    sPc[w-4][4][lane] += d4t;
  }
  __syncthreads();

  // ---- epilogue (all waves redundantly; tid 0 publishes)
  float qws[4], d0s[4];
  float qmr[4] = {qm0, qm1, qm2, qm3};
  #pragma unroll
  for (int reg = 0; reg < 4; ++reg) {
    int r = quad * 4 + reg;
    float ssr = 0.f, ddr = 0.f;
    #pragma unroll
    for (int k = 0; k < 8; ++k) { ssr += sSS[k][r]; ddr += sDD[k][r]; }
    qws[reg] = qmr[reg] / fmaxf(sqrtf(ssr), 1e-12f);
    d0s[reg] = ddr;
  }
  float an[4] = {0,0,0,0}, ad[4] = {0,0,0,0};
  #pragma unroll
  for (int t = 0; t < 5; ++t) {
    f32x4 v = sPc[0][t][lane] + sPc[1][t][lane]
            + sPc[2][t][lane] + sPc[3][t][lane];
    int j = i0 - 32 + 16 * t + l15;
    float vmask = ((unsigned)j < SS) ? 1.0f : 0.0f;
    int idxb = 16 * t + l15 - 1;        // = (j - i0) + 31
    #pragma unroll
    for (int reg = 0; reg < 4; ++reg) {
      float sv = v[reg] * qws[reg];     // kw baked into Khs
      int idx = min(max(idxb - quad * 4 - reg, 0), 63);
      float ev = (__expf(sv * tab_s[idx]) - 1.0f) * vmask;
      an[reg] += ev * sv;
      ad[reg] += ev;
    }
  }
  float tot = 0.f;
  #pragma unroll
  for (int reg = 0; reg < 4; ++reg) {
    float a = an[reg], e = ad[reg];
    a += __shfl_xor(a, 1, 64); a += __shfl_xor(a, 2, 64);
    a += __shfl_xor(a, 4, 64); a += __shfl_xor(a, 8, 64);
    e += __shfl_xor(e, 1, 64); e += __shfl_xor(e, 2, 64);
    e += __shfl_xor(e, 4, 64); e += __shfl_xor(e, 8, 64);
    tot += (qws[reg] * d0s[reg] + a) / (nk + e);
  }
  tot += __shfl_xor(tot, 16, 64);       // sum the 4 quads' row-groups
  tot += __shfl_xor(tot, 32, 64);
  if (tid == 0) {
    atomicAdd(&acc[b], tot);
    __threadfence();
    if (atomicAdd(&cnt[b], 1) == 127) { // last of 128 blocks for batch b
      float a2 = atomicAdd(&acc[b], 0.0f);
      out[b] = a2 / fmaxf(qsum[b], 1.0f);
    }
  }
}

extern "C" void kernel_launch(void* const* d_in, const int* in_sizes, int n_in,
                              void* d_out, int out_size, void* d_ws, size_t ws_size,
                              hipStream_t stream) {
  const float* Q    = (const float*)d_in[0];
  const float* K    = (const float*)d_in[1];
  const float* qm   = (const float*)d_in[2];
  const float* km   = (const float*)d_in[3];
  const float* temp = (const float*)d_in[4];
  float* outp = (float*)d_out;

  const size_t KHS_BYTES = (size_t)SB * SS * SH * 2;  // ~24 MB (fits ws, proven)
  __fp16* Khs = (__fp16*)d_ws;
  float* ksum = (float*)((char*)d_ws + KHS_BYTES);
  float* Nk   = ksum + SB * SH;
  float* qsum = Nk + 8;
  float* accb = qsum + 8;
  int*   cnt  = (int*)(accb + 8);

  (void)hipMemsetAsync(ksum, 0, (SB * SH + 32) * sizeof(float), stream);

  kprep_kernel<<<dim3(64, SB), 256, 0, stream>>>(K, km, qm, Khs, ksum, Nk, qsum);
  band_kernel<<<1024, 512, 0, stream>>>(Q, Khs, temp, qm, ksum, Nk,
                                        qsum, accb, cnt, outp);
}